// Round 1
// baseline (117.219 us; speedup 1.0000x reference)
//
#include <hip/hip_runtime.h>

// TokenEmbedding_51153060495497
// x: (256, 512, 7) f32;  kernels: (74, 8, 3) f32; keff = kernels[:,:,1]
// out flat: (256*513, 512) f32
//   row r = b*513 + t;  f in [0,512):
//     f < 511 : c = f/73, k = f%73
//     f == 511: c = 0,    k = 73
//   out[r*512+f] = sum_j xp[b, t+j, c] * keff[k, j],  xp = x zero-padded by 4 on L

#define CDIM 7
#define LDIM 512
#define TROWS 513            // L+1
#define ROWS_PER_BLOCK 32    // 131328 / 32 = 4104 blocks

__global__ __launch_bounds__(256) void tok_conv_kernel(
    const float* __restrict__ x,     // (256,512,7)
    const float* __restrict__ kern,  // (74,8,3)
    float* __restrict__ out)         // (131328, 512)
{
  const int tid  = threadIdx.x;
  const int q    = tid & 127;     // which float4 within the row
  const int rpar = tid >> 7;      // row parity within the block pair
  const int f0   = q * 4;

  // ---- per-thread constant setup (row-independent) ----
  // the 4 outputs span at most 2 channels: cLo (of f0) and cHi (of f0+3).
  const int cLo = f0 / 73;
  const int f3  = f0 + 3;
  const int cHi = (f3 == 511) ? 0 : (f3 / 73);

  float kLo[4][8], kHi[4][8];
#pragma unroll
  for (int i = 0; i < 4; ++i) {
    const int fi = f0 + i;
    const int ci = (fi == 511) ? 0 : (fi / 73);
    const int ki = (fi == 511) ? 73 : (fi - 73 * ci);
    const bool hi = (ci != cLo);
#pragma unroll
    for (int j = 0; j < 8; ++j) {
      const float kv = kern[ki * 24 + j * 3 + 1];  // kernels[ki, j, 1]
      kLo[i][j] = hi ? 0.f : kv;
      kHi[i][j] = hi ? kv : 0.f;
    }
  }

  const int rowBase = blockIdx.x * ROWS_PER_BLOCK;

#pragma unroll 1
  for (int it = 0; it < ROWS_PER_BLOCK; it += 2) {
    const int row = rowBase + it + rpar;
    const int b   = row / TROWS;
    const int t   = row - b * TROWS;
    const float* xb = x + (long)b * (LDIM * CDIM);

    // window loads: xp[b, t+j, cLo/cHi], j = 0..7 (zero outside [0,512))
    float w0[8], w1[8];
#pragma unroll
    for (int j = 0; j < 8; ++j) {
      const int p   = t + j - 4;
      const bool ok = ((unsigned)p) < 512u;
      const int base = p * CDIM;
      w0[j] = ok ? xb[base + cLo] : 0.f;
      w1[j] = ok ? xb[base + cHi] : 0.f;
    }

    float acc[4];
#pragma unroll
    for (int i = 0; i < 4; ++i) {
      float s = 0.f;
#pragma unroll
      for (int j = 0; j < 8; ++j) {
        s = fmaf(w0[j], kLo[i][j], s);
        s = fmaf(w1[j], kHi[i][j], s);
      }
      acc[i] = s;
    }

    reinterpret_cast<float4*>(out)[(long)row * 128 + q] =
        make_float4(acc[0], acc[1], acc[2], acc[3]);
  }
}

extern "C" void kernel_launch(void* const* d_in, const int* in_sizes, int n_in,
                              void* d_out, int out_size, void* d_ws, size_t ws_size,
                              hipStream_t stream) {
  const float* x    = (const float*)d_in[0];
  const float* kern = (const float*)d_in[1];
  float* out        = (float*)d_out;

  const int totalRows = 256 * TROWS;               // 131328
  const int nBlocks   = totalRows / ROWS_PER_BLOCK; // 4104
  tok_conv_kernel<<<nBlocks, 256, 0, stream>>>(x, kern, out);
}

// Round 2
// 95.186 us; speedup vs baseline: 1.2315x; 1.2315x over previous
//
#include <hip/hip_runtime.h>

// TokenEmbedding_51153060495497
// x: (256, 512, 7) f32;  kernels: (74, 8, 3) f32; keff = kernels[:,:,1]
// out flat: (256*513, 512) f32
//   row r = b*513 + t;  f in [0,512):
//     f < 511 : c = f/73, k = f%73
//     f == 511: c = 0,    k = 73
//   out[r*512+f] = sum_j xp[b, t+j-4, c] * keff[k, j]  (xp zero outside [0,512))

typedef float v2f __attribute__((ext_vector_type(2)));

#define CDIM 7
#define LDIM 512
#define TROWS 513
#define ROWS_PER_BLOCK 64   // 131328 / 64 = 2052 blocks

__global__ __launch_bounds__(256, 4) void tok_conv_kernel(
    const float* __restrict__ x,     // (256,512,7)
    const float* __restrict__ kern,  // (74,8,3)
    float* __restrict__ out)         // (131328, 512)
{
  const int tid  = threadIdx.x;
  const int q    = tid & 127;   // float4 slot within the row
  const int rpar = tid >> 7;    // row parity (uniform per wave64)
  const int f0   = q * 4;

  // ---- per-thread constants (row-independent) ----
  const int  cLo   = f0 / 73;            // channel of output f0
  const bool is127 = (q == 127);         // owns the f=511 special output
  const int  cOffX = cLo;
  // hi-channel offset: adjacent channel, or ch0 for the f=511 special,
  // or harmlessly aliased to cLo when no hi channel exists (weights are 0).
  const int  cOffY = is127 ? 0 : (cLo < 6 ? cLo + 1 : cLo);

  // packed weights: kP[i][j] = (w_lo, w_hi), exactly one slot nonzero
  v2f kP[4][8];
#pragma unroll
  for (int i = 0; i < 4; ++i) {
    const int fi = f0 + i;
    int ci, ki;
    if (fi == 511) { ci = 0; ki = 73; }
    else           { ci = fi / 73; ki = fi - 73 * ci; }
    const bool hi = (fi == 511) || (ci != cLo);
#pragma unroll
    for (int j = 0; j < 8; ++j) {
      const float kv = kern[ki * 24 + j * 3 + 1];  // kernels[ki, j, 1]
      kP[i][j].x = hi ? 0.f : kv;
      kP[i][j].y = hi ? kv : 0.f;
    }
  }

  const int rowBase = blockIdx.x * ROWS_PER_BLOCK;

#pragma unroll 1
  for (int it = 0; it < ROWS_PER_BLOCK; it += 2) {
    // row is uniform across the wave -> force scalar addressing
    const int row = __builtin_amdgcn_readfirstlane(rowBase + it + rpar);
    const int b   = row / TROWS;
    const int t   = row - b * TROWS;
    const float* rb = x + b * (LDIM * CDIM) + (t - 4) * CDIM;  // window base (uniform)

    v2f w[8];
    if (t >= 4 && t <= 508) {            // scalar branch: all 8 taps in-bounds
#pragma unroll
      for (int j = 0; j < 8; ++j) {
        w[j].x = rb[j * CDIM + cOffX];
        w[j].y = rb[j * CDIM + cOffY];
      }
    } else {                             // 8 of 513 rows: per-tap scalar guards
#pragma unroll
      for (int j = 0; j < 8; ++j) {
        const int p = t + j - 4;
        if ((unsigned)p < 512u) {
          w[j].x = rb[j * CDIM + cOffX];
          w[j].y = rb[j * CDIM + cOffY];
        } else {
          w[j].x = 0.f; w[j].y = 0.f;
        }
      }
    }

    v2f acc2[4] = {};
#pragma unroll
    for (int j = 0; j < 8; ++j) {
#pragma unroll
      for (int i = 0; i < 4; ++i) {
        acc2[i] += w[j] * kP[i][j];      // v_pk_fma_f32
      }
    }

    float4 o;
    o.x = acc2[0].x + acc2[0].y;
    o.y = acc2[1].x + acc2[1].y;
    o.z = acc2[2].x + acc2[2].y;
    o.w = acc2[3].x + acc2[3].y;
    reinterpret_cast<float4*>(out + (size_t)row * 512)[q] = o;
  }
}

extern "C" void kernel_launch(void* const* d_in, const int* in_sizes, int n_in,
                              void* d_out, int out_size, void* d_ws, size_t ws_size,
                              hipStream_t stream) {
  const float* x    = (const float*)d_in[0];
  const float* kern = (const float*)d_in[1];
  float* out        = (float*)d_out;

  const int totalRows = 256 * TROWS;                 // 131328
  const int nBlocks   = totalRows / ROWS_PER_BLOCK;  // 2052
  tok_conv_kernel<<<nBlocks, 256, 0, stream>>>(x, kern, out);
}

// Round 4
// 80.781 us; speedup vs baseline: 1.4511x; 1.1783x over previous
//
#include <hip/hip_runtime.h>

// TokenEmbedding_51153060495497
// x: (256, 512, 7) f32;  kernels: (74, 8, 3) f32; keff = kernels[:,:,1]
// out flat: (256*513, 512) f32
//   row r = b*513 + t;  f in [0,512):
//     f < 511 : c = f/73, k = f%73
//     f == 511: c = 0,    k = 73
//   out[r*512+f] = sum_j xp[b, t+j-4, c] * keff[k, j]  (xp zero outside [0,512))
//
// Sliding-window version: each thread owns one q-slot (4 consecutive features)
// for a stream of rows t, t+2, t+4, ... within one batch. The 8-tap window
// shifts by 2 per row -> 4 fresh loads/row instead of 16, issued as prefetch.

typedef float v2f __attribute__((ext_vector_type(2)));
typedef float v4f __attribute__((ext_vector_type(4)));

#define CDIM 7
#define LDIM 512
#define TROWS 513

__global__ __launch_bounds__(256, 4) void tok_conv_kernel(
    const float* __restrict__ x,     // (256,512,7)
    const float* __restrict__ kern,  // (74,8,3)
    float* __restrict__ out)         // (131328, 512)
{
  const int tid  = threadIdx.x;
  const int q    = tid & 127;   // float4 slot within the row
  const int rpar = tid >> 7;    // row parity (wave-uniform)
  const int f0   = q * 4;

  // ---- per-thread constants ----
  const int  cLo   = f0 / 73;
  const bool is127 = (q == 127);
  const int  cOffX = cLo;
  const int  cOffY = is127 ? 0 : (cLo < 6 ? cLo + 1 : cLo);

  // packed weights: kP[i][j] = (w_lo, w_hi), exactly one slot nonzero
  v2f kP[4][8];
#pragma unroll
  for (int i = 0; i < 4; ++i) {
    const int fi = f0 + i;
    int ci, ki;
    if (fi == 511) { ci = 0; ki = 73; }
    else           { ci = fi / 73; ki = fi - 73 * ci; }
    const bool hi = (fi == 511) || (ci != cLo);
#pragma unroll
    for (int j = 0; j < 8; ++j) {
      const float kv = kern[ki * 24 + j * 3 + 1];  // kernels[ki, j, 1]
      kP[i][j].x = hi ? 0.f : kv;
      kP[i][j].y = hi ? kv : 0.f;
    }
  }

  const int b     = blockIdx.y;   // batch
  const int chunk = blockIdx.x;   // 0..8
  const float* xb = x + b * (LDIM * CDIM);

  // ---- chunk 8: the single t=512 row per batch ----
  if (chunk == 8) {
    if (rpar) return;
    const int t = 512;
    v2f w[8];
#pragma unroll
    for (int j = 0; j < 8; ++j) {
      const int p   = t + j - 4;
      const bool ok = (unsigned)p < 512u;
      const int bse = (ok ? p : 0) * CDIM;
      w[j].x = ok ? xb[bse + cOffX] : 0.f;
      w[j].y = ok ? xb[bse + cOffY] : 0.f;
    }
    v2f acc2[4] = {};
#pragma unroll
    for (int j = 0; j < 8; ++j)
#pragma unroll
      for (int i = 0; i < 4; ++i) acc2[i] += w[j] * kP[i][j];
    v4f o = {acc2[0].x + acc2[0].y, acc2[1].x + acc2[1].y,
             acc2[2].x + acc2[2].y, acc2[3].x + acc2[3].y};
    __builtin_nontemporal_store(
        o, reinterpret_cast<v4f*>(out + ((size_t)b * TROWS + t) * 512) + q);
    return;
  }

  // ---- full 64-row chunk; this thread streams rows t0, t0+2, ..., t0+62 ----
  int t = chunk * 64 + rpar;

  // initial guarded window: taps p = t-4 .. t+3
  v2f w[8];
#pragma unroll
  for (int j = 0; j < 8; ++j) {
    const int p   = t + j - 4;
    const bool ok = (unsigned)p < 512u;
    const int bse = (ok ? p : 0) * CDIM;
    w[j].x = ok ? xb[bse + cOffX] : 0.f;
    w[j].y = ok ? xb[bse + cOffY] : 0.f;
  }

  v4f* orow = reinterpret_cast<v4f*>(out + ((size_t)b * TROWS + t) * 512) + q;

#pragma unroll 1
  for (int s4 = 0; s4 < 8; ++s4) {   // 8 groups x 4 steps = 32 rows
#pragma unroll
    for (int u = 0; u < 4; ++u) {
      const int base = 2 * u;        // compile-time window rotation

      // prefetch taps for row t+2: p = t+4, t+5 (clamped + zero-masked)
      const int p0 = t + 4, p1 = t + 5;
      const bool ok0 = p0 < 512, ok1 = p1 < 512;
      const int o0 = (ok0 ? p0 : 0) * CDIM;
      const int o1 = (ok1 ? p1 : 0) * CDIM;
      float n0x = xb[o0 + cOffX], n0y = xb[o0 + cOffY];
      float n1x = xb[o1 + cOffX], n1y = xb[o1 + cOffY];
      n0x = ok0 ? n0x : 0.f;  n0y = ok0 ? n0y : 0.f;
      n1x = ok1 ? n1x : 0.f;  n1y = ok1 ? n1y : 0.f;

      // compute current row from rotated window
      v2f acc2[4] = {};
#pragma unroll
      for (int j = 0; j < 8; ++j) {
        const v2f wv = w[(base + j) & 7];
#pragma unroll
        for (int i = 0; i < 4; ++i) acc2[i] += wv * kP[i][j];  // v_pk_fma_f32
      }
      v4f o = {acc2[0].x + acc2[0].y, acc2[1].x + acc2[1].y,
               acc2[2].x + acc2[2].y, acc2[3].x + acc2[3].y};
      __builtin_nontemporal_store(o, orow);
      orow += 2 * 128;               // advance 2 rows (256 float4s)

      // slide: new taps replace the two oldest slots
      w[base & 7]       = (v2f){n0x, n0y};
      w[(base + 1) & 7] = (v2f){n1x, n1y};
      t += 2;
    }
  }
}

extern "C" void kernel_launch(void* const* d_in, const int* in_sizes, int n_in,
                              void* d_out, int out_size, void* d_ws, size_t ws_size,
                              hipStream_t stream) {
  const float* x    = (const float*)d_in[0];
  const float* kern = (const float*)d_in[1];
  float* out        = (float*)d_out;

  dim3 grid(9, 256);   // 8 full 64-row chunks + 1 tail chunk (t=512), per batch
  tok_conv_kernel<<<grid, 256, 0, stream>>>(x, kern, out);
}

// Round 5
// 66.963 us; speedup vs baseline: 1.7505x; 1.2064x over previous
//
#include <hip/hip_runtime.h>

// TokenEmbedding_51153060495497
// x: (256, 512, 7) f32;  kernels: (74, 8, 3) f32; keff = kernels[:,:,1]
// out flat: (256*513, 512) f32
//   row r = b*513 + t;  f in [0,512):
//     f < 511 : c = f/73, k = f%73
//     f == 511: c = 0,    k = 73
//   out[r*512+f] = sum_j xp[b, t+j-4, c] * keff[k, j]  (xp zero outside [0,512))
//
// LDS-staged sliding-window: block stages its 74-row x window into LDS once
// (zero-padded), then the 32-step stream loop reads 4 taps/step from LDS with
// immediate offsets. No global loads, no bounds masks in the loop.

typedef float v2f __attribute__((ext_vector_type(2)));
typedef float v4f __attribute__((ext_vector_type(4)));

#define CDIM 7
#define LDIM 512
#define TROWS 513
#define WIN_ROWS 74
#define WIN_ELEMS (WIN_ROWS * CDIM)   // 518

__global__ __launch_bounds__(256, 4) void tok_conv_kernel(
    const float* __restrict__ x,     // (256,512,7)
    const float* __restrict__ kern,  // (74,8,3)
    float* __restrict__ out)         // (131328, 512)
{
  __shared__ float lds[WIN_ELEMS];

  const int tid  = threadIdx.x;
  const int q    = tid & 127;   // float4 slot within the row
  const int rpar = tid >> 7;    // row parity (wave-uniform)
  const int f0   = q * 4;

  // ---- per-thread constants ----
  const int  cLo   = f0 / 73;
  const bool is127 = (q == 127);
  const int  cOffX = cLo;
  const int  cOffY = is127 ? 0 : (cLo < 6 ? cLo + 1 : cLo);

  // packed weights: kP[i][j] = (w_lo, w_hi), exactly one slot nonzero
  v2f kP[4][8];
#pragma unroll
  for (int i = 0; i < 4; ++i) {
    const int fi = f0 + i;
    int ci, ki;
    if (fi == 511) { ci = 0; ki = 73; }
    else           { ci = fi / 73; ki = fi - 73 * ci; }
    const bool hi = (fi == 511) || (ci != cLo);
#pragma unroll
    for (int j = 0; j < 8; ++j) {
      const float kv = kern[ki * 24 + j * 3 + 1];  // kernels[ki, j, 1]
      kP[i][j].x = hi ? 0.f : kv;
      kP[i][j].y = hi ? kv : 0.f;
    }
  }

  const int b     = blockIdx.y;   // batch
  const int chunk = blockIdx.x;   // 0..8
  const float* xb = x + b * (LDIM * CDIM);

  // ---- chunk 8: the single t=512 row per batch (global reads, no LDS) ----
  if (chunk == 8) {
    if (rpar) return;
    const int t = 512;
    v2f w[8];
#pragma unroll
    for (int j = 0; j < 8; ++j) {
      const int p   = t + j - 4;
      const bool ok = (unsigned)p < 512u;
      const int bse = (ok ? p : 0) * CDIM;
      w[j].x = ok ? xb[bse + cOffX] : 0.f;
      w[j].y = ok ? xb[bse + cOffY] : 0.f;
    }
    v2f acc2[4] = {};
#pragma unroll
    for (int j = 0; j < 8; ++j)
#pragma unroll
      for (int i = 0; i < 4; ++i) acc2[i] += w[j] * kP[i][j];
    v4f o = {acc2[0].x + acc2[0].y, acc2[1].x + acc2[1].y,
             acc2[2].x + acc2[2].y, acc2[3].x + acc2[3].y};
    reinterpret_cast<v4f*>(out + ((size_t)b * TROWS + t) * 512)[q] = o;
    return;
  }

  const int t0 = chunk * 64;

  // ---- stage x[t0-4 .. t0+69] x 7ch into LDS (zero-padded, coalesced) ----
#pragma unroll
  for (int i = tid; i < WIN_ELEMS; i += 256) {
    const int r = i / CDIM;
    const int c = i - r * CDIM;
    const int p = t0 - 4 + r;
    lds[i] = ((unsigned)p < 512u) ? xb[p * CDIM + c] : 0.f;
  }
  __syncthreads();

  // per-thread LDS bases (element units); tap j of step s lives at
  // base + (rpar + 2*s + j)*7
  const int baseX = rpar * CDIM + cOffX;
  const int baseY = rpar * CDIM + cOffY;

  // initial window: taps j = 0..7 of step 0
  v2f w[8];
#pragma unroll
  for (int j = 0; j < 8; ++j) {
    w[j].x = lds[baseX + j * CDIM];
    w[j].y = lds[baseY + j * CDIM];
  }

  v4f* orow =
      reinterpret_cast<v4f*>(out + ((size_t)b * TROWS + t0 + rpar) * 512) + q;

  int bx = baseX, by = baseY;     // advance by 56 elements per 4-step group

#pragma unroll 1
  for (int s4 = 0; s4 < 8; ++s4) {   // 8 groups x 4 steps = 32 rows/thread
#pragma unroll
    for (int u = 0; u < 4; ++u) {
      const int base = 2 * u;        // compile-time window rotation

      // prefetch next row's 2 new taps from LDS (immediate offsets)
      v2f n0, n1;
      n0.x = lds[bx + (2 * u + 8) * CDIM];
      n0.y = lds[by + (2 * u + 8) * CDIM];
      n1.x = lds[bx + (2 * u + 9) * CDIM];
      n1.y = lds[by + (2 * u + 9) * CDIM];

      // compute current row from rotated window
      v2f acc2[4] = {};
#pragma unroll
      for (int j = 0; j < 8; ++j) {
        const v2f wv = w[(base + j) & 7];
#pragma unroll
        for (int i = 0; i < 4; ++i) acc2[i] += wv * kP[i][j];  // v_pk_fma_f32
      }
      v4f o = {acc2[0].x + acc2[0].y, acc2[1].x + acc2[1].y,
               acc2[2].x + acc2[2].y, acc2[3].x + acc2[3].y};
      *orow = o;
      orow += 2 * 128;               // advance 2 rows

      // slide: new taps replace the two oldest slots
      w[base & 7]       = n0;
      w[(base + 1) & 7] = n1;
    }
    bx += 8 * CDIM;                  // 4 steps x 2 rows
    by += 8 * CDIM;
  }
}

extern "C" void kernel_launch(void* const* d_in, const int* in_sizes, int n_in,
                              void* d_out, int out_size, void* d_ws, size_t ws_size,
                              hipStream_t stream) {
  const float* x    = (const float*)d_in[0];
  const float* kern = (const float*)d_in[1];
  float* out        = (float*)d_out;

  dim3 grid(9, 256);   // 8 full 64-row chunks + 1 tail chunk (t=512), per batch
  tok_conv_kernel<<<grid, 256, 0, stream>>>(x, kern, out);
}